// Round 10
// baseline (563.074 us; speedup 1.0000x reference)
//
#include <hip/hip_runtime.h>
#include <hip/hip_cooperative_groups.h>
#include <stdint.h>

namespace cg = cooperative_groups;

#define L_SEQ   2048
#define NBATCH  4
#define DM      512
#define DS      16
#define DR      32
#define NBDN    32768         // NBATCH*DM*DS chains
#define NCH     32            // chunks
#define CL      64            // chunk length
#define LOG2E   1.4426950408889634f

// unit counts per phase
#define U_PREP  128
#define U_FRONT 1024
#define U_SCAN  1024
#define U_PFX   128

// ws layout (float offsets)
#define WS_DX    0            // 4194304  packed (bf16 dt | bf16 xc) [b,l][d]
#define WS_XDBL  4194304      // 524288   x_dbl [row][64] (dt-raw | B | C) f32
#define WS_WXT   4718592      // 32768    WxT[d][j]
#define WS_WDTT  4751360      // 16384    WdtT[r][d]
#define WS_A2    4767744      // 8192     A2[d][n] = -exp(A_log)*log2e
#define WS_DTSUM 4775936      // 65536    dtsum[c][b*DM+d]
#define WS_S     4841472      // 1048576  S[c][chain]; prefix rewrites in-place to Hin
// total 5890048 floats = 23.6 MB

__device__ __forceinline__ uint32_t bf16_rne_hi(float v) {   // bf16 in high 16 bits
    uint32_t u = __float_as_uint(v);
    u += 0x7FFF + ((u >> 16) & 1);
    return u & 0xFFFF0000u;
}

// ================= phase unit bodies (shared by mega + fallback) =================

__device__ __forceinline__ void prep_unit(int u, int t,
        const float* __restrict__ Wx, const float* __restrict__ Wdt,
        const float* __restrict__ A_log, float* __restrict__ WxT,
        float* __restrict__ WdtT, float* __restrict__ A2) {
    int idx = u * 256 + t;
    if (idx < DM * 64) {                 // WxT[d][j] = Wx[j][d]
        int dd = idx >> 6, j = idx & 63;
        WxT[idx] = Wx[j * DM + dd];
    }
    if (idx < DR * DM) {                 // WdtT[r][d] = Wdt[d][r]
        int r = idx >> 9, dd = idx & 511;
        WdtT[idx] = Wdt[dd * DR + r];
    }
    if (idx < DM * DS)
        A2[idx] = -__expf(A_log[idx]) * LOG2E;
}

__device__ __forceinline__ void front_unit(int u, int t,
        const float* __restrict__ x, const float* __restrict__ convw,
        const float* __restrict__ convb, const float* __restrict__ WxT,
        const float* __restrict__ WdtT, const float* __restrict__ dtb,
        uint32_t* __restrict__ dx, float* __restrict__ xdbl,
        float (&xcs)[8][512], float (&pt)[4][8][64], float (&xds)[8][64]) {
    int r0 = u * 8;
    int b  = r0 >> 11, l0 = r0 & (L_SEQ - 1);
    int dq = t & 127, half = t >> 7;

    // ---- conv ----
    {
        const float4* wp = (const float4*)convw;
        float4 w0 = wp[dq * 4 + 0], w1 = wp[dq * 4 + 1];
        float4 w2 = wp[dq * 4 + 2], w3 = wp[dq * 4 + 3];
        float4 bias = ((const float4*)convb)[dq];
        #pragma unroll
        for (int i = 0; i < 4; ++i) {
            int row = half * 4 + i;
            int l   = l0 + row;
            const float* xr = x + ((size_t)(b * L_SEQ + l)) * DM + dq * 4;
            float4 acc = bias;
            float4 xv = *(const float4*)xr;
            acc.x = fmaf(xv.x, w0.w, acc.x); acc.y = fmaf(xv.y, w1.w, acc.y);
            acc.z = fmaf(xv.z, w2.w, acc.z); acc.w = fmaf(xv.w, w3.w, acc.w);
            if (l >= 1) {
                xv = *(const float4*)(xr - DM);
                acc.x = fmaf(xv.x, w0.z, acc.x); acc.y = fmaf(xv.y, w1.z, acc.y);
                acc.z = fmaf(xv.z, w2.z, acc.z); acc.w = fmaf(xv.w, w3.z, acc.w);
            }
            if (l >= 2) {
                xv = *(const float4*)(xr - 2 * DM);
                acc.x = fmaf(xv.x, w0.y, acc.x); acc.y = fmaf(xv.y, w1.y, acc.y);
                acc.z = fmaf(xv.z, w2.y, acc.z); acc.w = fmaf(xv.w, w3.y, acc.w);
            }
            if (l >= 3) {
                xv = *(const float4*)(xr - 3 * DM);
                acc.x = fmaf(xv.x, w0.x, acc.x); acc.y = fmaf(xv.y, w1.x, acc.y);
                acc.z = fmaf(xv.z, w2.x, acc.z); acc.w = fmaf(xv.w, w3.x, acc.w);
            }
            *(float4*)(&xcs[row][dq * 4]) = acc;
        }
    }
    __syncthreads();

    // ---- proj1: wave wv owns K-slice [wv*128, wv*128+128) ----
    {
        int wv = t >> 6, j = t & 63;
        int k0 = wv * 128;
        float acc[8] = {0.f, 0.f, 0.f, 0.f, 0.f, 0.f, 0.f, 0.f};
        const float* wp = WxT + (size_t)k0 * 64 + j;
        for (int k4 = 0; k4 < 32; ++k4) {
            float4 xr[8];
            #pragma unroll
            for (int ri = 0; ri < 8; ++ri)
                xr[ri] = *(const float4*)(&xcs[ri][k0 + k4 * 4]);  // wave-uniform
            #pragma unroll
            for (int kk = 0; kk < 4; ++kk) {
                float w = wp[(k4 * 4 + kk) * 64];
                acc[0] = fmaf(((const float*)&xr[0])[kk], w, acc[0]);
                acc[1] = fmaf(((const float*)&xr[1])[kk], w, acc[1]);
                acc[2] = fmaf(((const float*)&xr[2])[kk], w, acc[2]);
                acc[3] = fmaf(((const float*)&xr[3])[kk], w, acc[3]);
                acc[4] = fmaf(((const float*)&xr[4])[kk], w, acc[4]);
                acc[5] = fmaf(((const float*)&xr[5])[kk], w, acc[5]);
                acc[6] = fmaf(((const float*)&xr[6])[kk], w, acc[6]);
                acc[7] = fmaf(((const float*)&xr[7])[kk], w, acc[7]);
            }
        }
        #pragma unroll
        for (int ri = 0; ri < 8; ++ri) pt[wv][ri][j] = acc[ri];
    }
    __syncthreads();

    // ---- reduce K-slices -> xds + global xdbl ----
    #pragma unroll
    for (int o = t; o < 512; o += 256) {
        int row = o >> 6, j2 = o & 63;
        float s = (pt[0][row][j2] + pt[1][row][j2])
                + (pt[2][row][j2] + pt[3][row][j2]);
        xds[row][j2] = s;
        xdbl[(size_t)(r0 + row) * 64 + j2] = s;
    }
    __syncthreads();

    // ---- proj2 + softplus + pack (dt|xc) bf16 ----
    {
        float4 bias = ((const float4*)dtb)[dq];
        float4 z0 = bias, z1 = bias, z2 = bias, z3 = bias;
        for (int r = 0; r < DR; ++r) {
            float4 w4 = *(const float4*)(WdtT + r * DM + dq * 4);
            float x0 = xds[half * 4 + 0][r];
            float x1 = xds[half * 4 + 1][r];
            float x2 = xds[half * 4 + 2][r];
            float x3 = xds[half * 4 + 3][r];
            z0.x = fmaf(x0, w4.x, z0.x); z0.y = fmaf(x0, w4.y, z0.y);
            z0.z = fmaf(x0, w4.z, z0.z); z0.w = fmaf(x0, w4.w, z0.w);
            z1.x = fmaf(x1, w4.x, z1.x); z1.y = fmaf(x1, w4.y, z1.y);
            z1.z = fmaf(x1, w4.z, z1.z); z1.w = fmaf(x1, w4.w, z1.w);
            z2.x = fmaf(x2, w4.x, z2.x); z2.y = fmaf(x2, w4.y, z2.y);
            z2.z = fmaf(x2, w4.z, z2.z); z2.w = fmaf(x2, w4.w, z2.w);
            z3.x = fmaf(x3, w4.x, z3.x); z3.y = fmaf(x3, w4.y, z3.y);
            z3.z = fmaf(x3, w4.z, z3.z); z3.w = fmaf(x3, w4.w, z3.w);
        }
        float4 zz[4] = {z0, z1, z2, z3};
        #pragma unroll
        for (int i = 0; i < 4; ++i) {
            int row = half * 4 + i;
            float4 zi = zz[i];
            float4 sp;
            sp.x = fmaxf(zi.x, 0.f) + log1pf(__expf(-fabsf(zi.x)));
            sp.y = fmaxf(zi.y, 0.f) + log1pf(__expf(-fabsf(zi.y)));
            sp.z = fmaxf(zi.z, 0.f) + log1pf(__expf(-fabsf(zi.z)));
            sp.w = fmaxf(zi.w, 0.f) + log1pf(__expf(-fabsf(zi.w)));
            uint4 pk;
            pk.x = bf16_rne_hi(sp.x) | (bf16_rne_hi(xcs[row][dq * 4 + 0]) >> 16);
            pk.y = bf16_rne_hi(sp.y) | (bf16_rne_hi(xcs[row][dq * 4 + 1]) >> 16);
            pk.z = bf16_rne_hi(sp.z) | (bf16_rne_hi(xcs[row][dq * 4 + 2]) >> 16);
            pk.w = bf16_rne_hi(sp.w) | (bf16_rne_hi(xcs[row][dq * 4 + 3]) >> 16);
            *(uint4*)(dx + ((size_t)(b * L_SEQ + l0 + row)) * DM + dq * 4) = pk;
        }
    }
    __syncthreads();   // protect xcs/xds before next grid-stride iteration
}

__device__ __forceinline__ void scan1_unit(int u, int t,
        const uint32_t* __restrict__ dx, const float* __restrict__ xdbl,
        const float* __restrict__ A2, float* __restrict__ S,
        float* __restrict__ dtsum) {
    int lane   = t & 63;
    int wv     = t >> 6;
    int dlocal = lane & 15;
    int nq     = lane >> 4;
    int db8    = u & 7;
    int c      = (u >> 3) & (NCH - 1);
    int b      = u >> 8;
    int d      = (db8 * 4 + wv) * 16 + dlocal;
    int l0     = c * CL;

    float4 a2 = *(const float4*)(A2 + (size_t)d * DS + nq * 4);
    float h0 = 0.f, h1 = 0.f, h2 = 0.f, h3 = 0.f;
    float dsum = 0.f;
    const uint32_t* dxp = dx + ((size_t)(b * L_SEQ + l0)) * DM + d;
    const float*    bp  = xdbl + ((size_t)(b * L_SEQ + l0)) * 64 + DR + nq * 4;

    #pragma unroll 4
    for (int i = 0; i < CL; ++i) {
        uint32_t v = dxp[(size_t)i * DM];
        float dt = __uint_as_float(v & 0xFFFF0000u);
        float xv = __uint_as_float(v << 16);
        float4 B4 = *(const float4*)(bp + (size_t)i * 64);
        float uu = dt * xv;
        dsum += dt;
        float dA;
        dA = exp2f(dt * a2.x); h0 = fmaf(dA, h0, uu * B4.x);
        dA = exp2f(dt * a2.y); h1 = fmaf(dA, h1, uu * B4.y);
        dA = exp2f(dt * a2.z); h2 = fmaf(dA, h2, uu * B4.z);
        dA = exp2f(dt * a2.w); h3 = fmaf(dA, h3, uu * B4.w);
    }
    float4 sv; sv.x = h0; sv.y = h1; sv.z = h2; sv.w = h3;
    *(float4*)(S + (size_t)c * NBDN + ((size_t)(b * DM + d)) * DS + nq * 4) = sv;
    if (nq == 0)
        dtsum[c * (NBATCH * DM) + b * DM + d] = dsum;
}

__device__ __forceinline__ void scan2_unit(int u, int t,
        const float* __restrict__ dtsum, const float* __restrict__ A2,
        float* __restrict__ S) {
    int t2 = u * 256 + t;                    // 0..32767
    float a2s = A2[t2 & (DM * DS - 1)];
    int bd = t2 >> 4;
    float H = 0.f;
    #pragma unroll 8
    for (int cc = 0; cc < NCH; ++cc) {
        float p = exp2f(a2s * dtsum[cc * (NBATCH * DM) + bd]);
        float s = S[(size_t)cc * NBDN + t2];
        S[(size_t)cc * NBDN + t2] = H;       // Hin for chunk cc
        H = fmaf(p, H, s);
    }
}

__device__ __forceinline__ void scan3_unit(int u, int t,
        const uint32_t* __restrict__ dx, const float* __restrict__ xdbl,
        const float* __restrict__ A2, const float* __restrict__ Dvec,
        const float* __restrict__ Hin, float* __restrict__ out) {
    int lane   = t & 63;
    int wv     = t >> 6;
    int dlocal = lane & 15;
    int nq     = lane >> 4;
    int db8    = u & 7;
    int c      = (u >> 3) & (NCH - 1);
    int b      = u >> 8;
    int d      = (db8 * 4 + wv) * 16 + dlocal;
    int l0     = c * CL;

    float4 a2 = *(const float4*)(A2 + (size_t)d * DS + nq * 4);
    float Dv = Dvec[d];
    float4 hv = *(const float4*)(Hin + (size_t)c * NBDN + ((size_t)(b * DM + d)) * DS + nq * 4);
    float h0 = hv.x, h1 = hv.y, h2 = hv.z, h3 = hv.w;

    const uint32_t* dxp = dx + ((size_t)(b * L_SEQ + l0)) * DM + d;
    const float*    bp  = xdbl + ((size_t)(b * L_SEQ + l0)) * 64 + DR + nq * 4;
    float* op = out + ((size_t)(b * L_SEQ + l0)) * DM + d;

    #pragma unroll 4
    for (int i = 0; i < CL; ++i) {
        uint32_t v = dxp[(size_t)i * DM];
        float dt = __uint_as_float(v & 0xFFFF0000u);
        float xv = __uint_as_float(v << 16);
        float4 B4 = *(const float4*)(bp + (size_t)i * 64);
        float4 C4 = *(const float4*)(bp + (size_t)i * 64 + DS);
        float uu = dt * xv;
        float dA;
        dA = exp2f(dt * a2.x); h0 = fmaf(dA, h0, uu * B4.x);
        dA = exp2f(dt * a2.y); h1 = fmaf(dA, h1, uu * B4.y);
        dA = exp2f(dt * a2.z); h2 = fmaf(dA, h2, uu * B4.z);
        dA = exp2f(dt * a2.w); h3 = fmaf(dA, h3, uu * B4.w);
        float p = fmaf(h3, C4.w, fmaf(h2, C4.z, fmaf(h1, C4.y, h0 * C4.x)));
        p += __shfl_xor(p, 16);
        p += __shfl_xor(p, 32);
        if (nq == 0) op[(size_t)i * DM] = fmaf(xv, Dv, p);
    }
}

// ================= cooperative mega-kernel (grid-stride phases) =================
__global__ void __launch_bounds__(256, 4) k_mega(
        const float* __restrict__ x, const float* __restrict__ A_log,
        const float* __restrict__ Dvec, const float* __restrict__ Wx,
        const float* __restrict__ Wdt, const float* __restrict__ dtb,
        const float* __restrict__ convw, const float* __restrict__ convb,
        float* __restrict__ out, float* __restrict__ ws) {
    __shared__ float xcs[8][512];
    __shared__ float pt[4][8][64];
    __shared__ float xds[8][64];
    cg::grid_group grid = cg::this_grid();

    uint32_t* dx    = (uint32_t*)(ws + WS_DX);
    float*    xdbl  = ws + WS_XDBL;
    float*    WxT   = ws + WS_WXT;
    float*    WdtT  = ws + WS_WDTT;
    float*    A2    = ws + WS_A2;
    float*    dtsum = ws + WS_DTSUM;
    float*    S     = ws + WS_S;

    int t  = threadIdx.x;
    int nb = gridDim.x;

    for (int u = blockIdx.x; u < U_PREP; u += nb)
        prep_unit(u, t, Wx, Wdt, A_log, WxT, WdtT, A2);
    __threadfence();
    grid.sync();

    for (int u = blockIdx.x; u < U_FRONT; u += nb)
        front_unit(u, t, x, convw, convb, WxT, WdtT, dtb, dx, xdbl, xcs, pt, xds);
    __threadfence();
    grid.sync();

    for (int u = blockIdx.x; u < U_SCAN; u += nb)
        scan1_unit(u, t, dx, xdbl, A2, S, dtsum);
    __threadfence();
    grid.sync();

    for (int u = blockIdx.x; u < U_PFX; u += nb)
        scan2_unit(u, t, dtsum, A2, S);
    __threadfence();
    grid.sync();

    for (int u = blockIdx.x; u < U_SCAN; u += nb)
        scan3_unit(u, t, dx, xdbl, A2, Dvec, S, out);
}

// ================= fallback kernels (R8-equivalent, proven) =================
__global__ void __launch_bounds__(256) kf_prep(
        const float* __restrict__ Wx, const float* __restrict__ Wdt,
        const float* __restrict__ A_log, float* __restrict__ WxT,
        float* __restrict__ WdtT, float* __restrict__ A2) {
    prep_unit(blockIdx.x, threadIdx.x, Wx, Wdt, A_log, WxT, WdtT, A2);
}
__global__ void __launch_bounds__(256) kf_front(
        const float* __restrict__ x, const float* __restrict__ convw,
        const float* __restrict__ convb, const float* __restrict__ WxT,
        const float* __restrict__ WdtT, const float* __restrict__ dtb,
        uint32_t* __restrict__ dx, float* __restrict__ xdbl) {
    __shared__ float xcs[8][512];
    __shared__ float pt[4][8][64];
    __shared__ float xds[8][64];
    front_unit(blockIdx.x, threadIdx.x, x, convw, convb, WxT, WdtT, dtb,
               dx, xdbl, xcs, pt, xds);
}
__global__ void __launch_bounds__(256) kf_scan1(
        const uint32_t* __restrict__ dx, const float* __restrict__ xdbl,
        const float* __restrict__ A2, float* __restrict__ S,
        float* __restrict__ dtsum) {
    scan1_unit(blockIdx.x, threadIdx.x, dx, xdbl, A2, S, dtsum);
}
__global__ void __launch_bounds__(256) kf_scan2(
        const float* __restrict__ dtsum, const float* __restrict__ A2,
        float* __restrict__ S) {
    scan2_unit(blockIdx.x, threadIdx.x, dtsum, A2, S);
}
__global__ void __launch_bounds__(256) kf_scan3(
        const uint32_t* __restrict__ dx, const float* __restrict__ xdbl,
        const float* __restrict__ A2, const float* __restrict__ Dvec,
        const float* __restrict__ Hin, float* __restrict__ out) {
    scan3_unit(blockIdx.x, threadIdx.x, dx, xdbl, A2, Dvec, Hin, out);
}

extern "C" void kernel_launch(void* const* d_in, const int* in_sizes, int n_in,
                              void* d_out, int out_size, void* d_ws, size_t ws_size,
                              hipStream_t stream) {
    const float* x      = (const float*)d_in[0];
    const float* A_log  = (const float*)d_in[1];
    const float* Dvec   = (const float*)d_in[2];
    const float* Wx     = (const float*)d_in[3];
    const float* Wdt    = (const float*)d_in[4];
    const float* dtb    = (const float*)d_in[5];
    const float* convw  = (const float*)d_in[6];
    const float* convb  = (const float*)d_in[7];
    float* out = (float*)d_out;
    float* wsf = (float*)d_ws;

    // deterministic host-side queries (capture-safe, no stream ops)
    int dev = 0;
    hipGetDevice(&dev);
    int coop = 0;
    hipDeviceGetAttribute(&coop, hipDeviceAttributeCooperativeLaunch, dev);
    int ncu = 0;
    hipDeviceGetAttribute(&ncu, hipDeviceAttributeMultiprocessorCount, dev);
    int occ = 0;
    hipOccupancyMaxActiveBlocksPerMultiprocessor(&occ, (const void*)k_mega, 256, 0);
    long maxb = (long)occ * (long)ncu;
    int grid = (int)(maxb < U_FRONT ? maxb : U_FRONT);

    if (coop && grid >= 256) {
        void* args[] = { (void*)&x, (void*)&A_log, (void*)&Dvec, (void*)&Wx,
                         (void*)&Wdt, (void*)&dtb, (void*)&convw, (void*)&convb,
                         (void*)&out, (void*)&wsf };
        hipLaunchCooperativeKernel((const void*)k_mega, dim3(grid), dim3(256),
                                   args, 0, stream);
    } else {
        uint32_t* dx    = (uint32_t*)(wsf + WS_DX);
        float*    xdbl  = wsf + WS_XDBL;
        float*    WxT   = wsf + WS_WXT;
        float*    WdtT  = wsf + WS_WDTT;
        float*    A2    = wsf + WS_A2;
        float*    dtsum = wsf + WS_DTSUM;
        float*    S     = wsf + WS_S;
        kf_prep<<<U_PREP, 256, 0, stream>>>(Wx, Wdt, A_log, WxT, WdtT, A2);
        kf_front<<<U_FRONT, 256, 0, stream>>>(x, convw, convb, WxT, WdtT, dtb, dx, xdbl);
        kf_scan1<<<U_SCAN, 256, 0, stream>>>(dx, xdbl, A2, S, dtsum);
        kf_scan2<<<U_PFX, 256, 0, stream>>>(dtsum, A2, S);
        kf_scan3<<<U_SCAN, 256, 0, stream>>>(dx, xdbl, A2, Dvec, S, out);
    }
}

// Round 11
// 131.016 us; speedup vs baseline: 4.2978x; 4.2978x over previous
//
#include <hip/hip_runtime.h>
#include <stdint.h>

#define L_SEQ   2048
#define NBATCH  4
#define DM      512
#define DS      16
#define DR      32
#define NBDN    32768         // NBATCH*DM*DS chains
#define NCH     32            // chunks
#define CL      64            // chunk length
#define LOG2E   1.4426950408889634f

// ws layout (float offsets)
#define WS_DX    0            // 4194304  packed (bf16 dt | bf16 xc) [b,l][d]
#define WS_XDBL  4194304      // 524288   x_dbl [row][64] (dt-raw | B | C) f32
#define WS_WXT   4718592      // 32768    WxT[d][j]
#define WS_WDTT  4751360      // 16384    WdtT[r][d]
#define WS_A2    4767744      // 8192     A2[d][n] = -exp(A_log)*log2e
#define WS_DTSUM 4775936      // 65536    dtsum[c][b*DM+d]
#define WS_S     4841472      // 1048576  S[c][chain] (read-only after scan1)
// total 5890048 floats = 23.6 MB

__device__ __forceinline__ uint32_t bf16_rne_hi(float v) {   // bf16 in high 16 bits
    uint32_t u = __float_as_uint(v);
    u += 0x7FFF + ((u >> 16) & 1);
    return u & 0xFFFF0000u;
}

// ---------------- prep: weight transposes + A2 ----------------
__global__ void __launch_bounds__(256) k_prep(
        const float* __restrict__ Wx, const float* __restrict__ Wdt,
        const float* __restrict__ A_log, float* __restrict__ WxT,
        float* __restrict__ WdtT, float* __restrict__ A2) {
    int idx = blockIdx.x * 256 + threadIdx.x;
    if (idx < DM * 64) {                 // WxT[d][j] = Wx[j][d]
        int dd = idx >> 6, j = idx & 63;
        WxT[idx] = Wx[j * DM + dd];
    }
    if (idx < DR * DM) {                 // WdtT[r][d] = Wdt[d][r]
        int r = idx >> 9, dd = idx & 511;
        WdtT[idx] = Wdt[dd * DR + r];
    }
    if (idx < DM * DS)
        A2[idx] = -__expf(A_log[idx]) * LOG2E;
}

// ---------------- front: conv + proj1 (K-split) + proj2 + bf16 pack ----------------
__global__ void __launch_bounds__(256) k_front(
        const float* __restrict__ x, const float* __restrict__ convw,
        const float* __restrict__ convb, const float* __restrict__ WxT,
        const float* __restrict__ WdtT, const float* __restrict__ dtb,
        uint32_t* __restrict__ dx, float* __restrict__ xdbl) {
    __shared__ float xcs[8][512];
    __shared__ float pt[4][8][64];
    __shared__ float xds[8][64];
    int t  = threadIdx.x;
    int r0 = blockIdx.x * 8;
    int b  = r0 >> 11, l0 = r0 & (L_SEQ - 1);
    int dq = t & 127, half = t >> 7;

    // ---- conv ----
    {
        const float4* wp = (const float4*)convw;
        float4 w0 = wp[dq * 4 + 0], w1 = wp[dq * 4 + 1];
        float4 w2 = wp[dq * 4 + 2], w3 = wp[dq * 4 + 3];
        float4 bias = ((const float4*)convb)[dq];
        #pragma unroll
        for (int i = 0; i < 4; ++i) {
            int row = half * 4 + i;
            int l   = l0 + row;
            const float* xr = x + ((size_t)(b * L_SEQ + l)) * DM + dq * 4;
            float4 acc = bias;
            float4 xv = *(const float4*)xr;
            acc.x = fmaf(xv.x, w0.w, acc.x); acc.y = fmaf(xv.y, w1.w, acc.y);
            acc.z = fmaf(xv.z, w2.w, acc.z); acc.w = fmaf(xv.w, w3.w, acc.w);
            if (l >= 1) {
                xv = *(const float4*)(xr - DM);
                acc.x = fmaf(xv.x, w0.z, acc.x); acc.y = fmaf(xv.y, w1.z, acc.y);
                acc.z = fmaf(xv.z, w2.z, acc.z); acc.w = fmaf(xv.w, w3.z, acc.w);
            }
            if (l >= 2) {
                xv = *(const float4*)(xr - 2 * DM);
                acc.x = fmaf(xv.x, w0.y, acc.x); acc.y = fmaf(xv.y, w1.y, acc.y);
                acc.z = fmaf(xv.z, w2.y, acc.z); acc.w = fmaf(xv.w, w3.y, acc.w);
            }
            if (l >= 3) {
                xv = *(const float4*)(xr - 3 * DM);
                acc.x = fmaf(xv.x, w0.x, acc.x); acc.y = fmaf(xv.y, w1.x, acc.y);
                acc.z = fmaf(xv.z, w2.x, acc.z); acc.w = fmaf(xv.w, w3.x, acc.w);
            }
            *(float4*)(&xcs[row][dq * 4]) = acc;
        }
    }
    __syncthreads();

    // ---- proj1: wave wv owns K-slice [wv*128, wv*128+128) ----
    {
        int wv = t >> 6, j = t & 63;
        int k0 = wv * 128;
        float acc[8] = {0.f, 0.f, 0.f, 0.f, 0.f, 0.f, 0.f, 0.f};
        const float* wp = WxT + (size_t)k0 * 64 + j;
        for (int k4 = 0; k4 < 32; ++k4) {
            float4 xr[8];
            #pragma unroll
            for (int ri = 0; ri < 8; ++ri)
                xr[ri] = *(const float4*)(&xcs[ri][k0 + k4 * 4]);  // wave-uniform
            #pragma unroll
            for (int kk = 0; kk < 4; ++kk) {
                float w = wp[(k4 * 4 + kk) * 64];
                acc[0] = fmaf(((const float*)&xr[0])[kk], w, acc[0]);
                acc[1] = fmaf(((const float*)&xr[1])[kk], w, acc[1]);
                acc[2] = fmaf(((const float*)&xr[2])[kk], w, acc[2]);
                acc[3] = fmaf(((const float*)&xr[3])[kk], w, acc[3]);
                acc[4] = fmaf(((const float*)&xr[4])[kk], w, acc[4]);
                acc[5] = fmaf(((const float*)&xr[5])[kk], w, acc[5]);
                acc[6] = fmaf(((const float*)&xr[6])[kk], w, acc[6]);
                acc[7] = fmaf(((const float*)&xr[7])[kk], w, acc[7]);
            }
        }
        #pragma unroll
        for (int ri = 0; ri < 8; ++ri) pt[wv][ri][j] = acc[ri];
    }
    __syncthreads();

    // ---- reduce K-slices -> xds + global xdbl ----
    #pragma unroll
    for (int o = t; o < 512; o += 256) {
        int row = o >> 6, j2 = o & 63;
        float s = (pt[0][row][j2] + pt[1][row][j2])
                + (pt[2][row][j2] + pt[3][row][j2]);
        xds[row][j2] = s;
        xdbl[(size_t)(r0 + row) * 64 + j2] = s;
    }
    __syncthreads();

    // ---- proj2 + softplus + pack (dt|xc) bf16 ----
    {
        float4 bias = ((const float4*)dtb)[dq];
        float4 z0 = bias, z1 = bias, z2 = bias, z3 = bias;
        for (int r = 0; r < DR; ++r) {
            float4 w4 = *(const float4*)(WdtT + r * DM + dq * 4);
            float x0 = xds[half * 4 + 0][r];
            float x1 = xds[half * 4 + 1][r];
            float x2 = xds[half * 4 + 2][r];
            float x3 = xds[half * 4 + 3][r];
            z0.x = fmaf(x0, w4.x, z0.x); z0.y = fmaf(x0, w4.y, z0.y);
            z0.z = fmaf(x0, w4.z, z0.z); z0.w = fmaf(x0, w4.w, z0.w);
            z1.x = fmaf(x1, w4.x, z1.x); z1.y = fmaf(x1, w4.y, z1.y);
            z1.z = fmaf(x1, w4.z, z1.z); z1.w = fmaf(x1, w4.w, z1.w);
            z2.x = fmaf(x2, w4.x, z2.x); z2.y = fmaf(x2, w4.y, z2.y);
            z2.z = fmaf(x2, w4.z, z2.z); z2.w = fmaf(x2, w4.w, z2.w);
            z3.x = fmaf(x3, w4.x, z3.x); z3.y = fmaf(x3, w4.y, z3.y);
            z3.z = fmaf(x3, w4.z, z3.z); z3.w = fmaf(x3, w4.w, z3.w);
        }
        float4 zz[4] = {z0, z1, z2, z3};
        #pragma unroll
        for (int i = 0; i < 4; ++i) {
            int row = half * 4 + i;
            float4 zi = zz[i];
            float4 sp;
            sp.x = fmaxf(zi.x, 0.f) + log1pf(__expf(-fabsf(zi.x)));
            sp.y = fmaxf(zi.y, 0.f) + log1pf(__expf(-fabsf(zi.y)));
            sp.z = fmaxf(zi.z, 0.f) + log1pf(__expf(-fabsf(zi.z)));
            sp.w = fmaxf(zi.w, 0.f) + log1pf(__expf(-fabsf(zi.w)));
            uint4 pk;
            pk.x = bf16_rne_hi(sp.x) | (bf16_rne_hi(xcs[row][dq * 4 + 0]) >> 16);
            pk.y = bf16_rne_hi(sp.y) | (bf16_rne_hi(xcs[row][dq * 4 + 1]) >> 16);
            pk.z = bf16_rne_hi(sp.z) | (bf16_rne_hi(xcs[row][dq * 4 + 2]) >> 16);
            pk.w = bf16_rne_hi(sp.w) | (bf16_rne_hi(xcs[row][dq * 4 + 3]) >> 16);
            *(uint4*)(dx + ((size_t)(b * L_SEQ + l0 + row)) * DM + dq * 4) = pk;
        }
    }
}

// ---------------- scan1: per-chunk local scan -> S, dtsum ----------------
__global__ void __launch_bounds__(256) k_scan1(
        const uint32_t* __restrict__ dx, const float* __restrict__ xdbl,
        const float* __restrict__ A2, float* __restrict__ S,
        float* __restrict__ dtsum) {
    int t      = threadIdx.x;
    int u      = blockIdx.x;
    int lane   = t & 63;
    int wv     = t >> 6;
    int dlocal = lane & 15;
    int nq     = lane >> 4;
    int db8    = u & 7;
    int c      = (u >> 3) & (NCH - 1);
    int b      = u >> 8;
    int d      = (db8 * 4 + wv) * 16 + dlocal;
    int l0     = c * CL;

    float4 a2 = *(const float4*)(A2 + (size_t)d * DS + nq * 4);
    float h0 = 0.f, h1 = 0.f, h2 = 0.f, h3 = 0.f;
    float dsum = 0.f;
    const uint32_t* dxp = dx + ((size_t)(b * L_SEQ + l0)) * DM + d;
    const float*    bp  = xdbl + ((size_t)(b * L_SEQ + l0)) * 64 + DR + nq * 4;

    #pragma unroll 8
    for (int i = 0; i < CL; ++i) {
        uint32_t v = dxp[(size_t)i * DM];
        float dt = __uint_as_float(v & 0xFFFF0000u);
        float xv = __uint_as_float(v << 16);
        float4 B4 = *(const float4*)(bp + (size_t)i * 64);
        float uu = dt * xv;
        dsum += dt;
        float dA;
        dA = exp2f(dt * a2.x); h0 = fmaf(dA, h0, uu * B4.x);
        dA = exp2f(dt * a2.y); h1 = fmaf(dA, h1, uu * B4.y);
        dA = exp2f(dt * a2.z); h2 = fmaf(dA, h2, uu * B4.z);
        dA = exp2f(dt * a2.w); h3 = fmaf(dA, h3, uu * B4.w);
    }
    float4 sv; sv.x = h0; sv.y = h1; sv.z = h2; sv.w = h3;
    *(float4*)(S + (size_t)c * NBDN + ((size_t)(b * DM + d)) * DS + nq * 4) = sv;
    if (nq == 0)
        dtsum[c * (NBATCH * DM) + b * DM + d] = dsum;
}

// ---------------- scan23: in-block prefix over chunks < c, then replay + y ----------------
__global__ void __launch_bounds__(256) k_scan23(
        const uint32_t* __restrict__ dx, const float* __restrict__ xdbl,
        const float* __restrict__ A2, const float* __restrict__ Dvec,
        const float* __restrict__ S, const float* __restrict__ dtsum,
        float* __restrict__ out) {
    int t      = threadIdx.x;
    int u      = blockIdx.x;
    int lane   = t & 63;
    int wv     = t >> 6;
    int dlocal = lane & 15;
    int nq     = lane >> 4;
    int db8    = u & 7;
    int c      = (u >> 3) & (NCH - 1);
    int b      = u >> 8;
    int d      = (db8 * 4 + wv) * 16 + dlocal;
    int l0     = c * CL;

    float4 a2 = *(const float4*)(A2 + (size_t)d * DS + nq * 4);
    float Dv  = Dvec[d];

    // ---- prefix: Hin(c) = fold over chunks 0..c-1 ----
    float h0 = 0.f, h1 = 0.f, h2 = 0.f, h3 = 0.f;
    {
        const float* dsp = dtsum + b * DM + d;
        const float* Sp  = S + ((size_t)(b * DM + d)) * DS + nq * 4;
        for (int cc = 0; cc < c; ++cc) {
            float ds  = dsp[cc * (NBATCH * DM)];
            float4 Sc = *(const float4*)(Sp + (size_t)cc * NBDN);
            float p;
            p = exp2f(a2.x * ds); h0 = fmaf(p, h0, Sc.x);
            p = exp2f(a2.y * ds); h1 = fmaf(p, h1, Sc.y);
            p = exp2f(a2.z * ds); h2 = fmaf(p, h2, Sc.z);
            p = exp2f(a2.w * ds); h3 = fmaf(p, h3, Sc.w);
        }
    }

    // ---- replay chunk, emit y ----
    const uint32_t* dxp = dx + ((size_t)(b * L_SEQ + l0)) * DM + d;
    const float*    bp  = xdbl + ((size_t)(b * L_SEQ + l0)) * 64 + DR + nq * 4;
    float* op = out + ((size_t)(b * L_SEQ + l0)) * DM + d;

    #pragma unroll 8
    for (int i = 0; i < CL; ++i) {
        uint32_t v = dxp[(size_t)i * DM];
        float dt = __uint_as_float(v & 0xFFFF0000u);
        float xv = __uint_as_float(v << 16);
        float4 B4 = *(const float4*)(bp + (size_t)i * 64);
        float4 C4 = *(const float4*)(bp + (size_t)i * 64 + DS);
        float uu = dt * xv;
        float dA;
        dA = exp2f(dt * a2.x); h0 = fmaf(dA, h0, uu * B4.x);
        dA = exp2f(dt * a2.y); h1 = fmaf(dA, h1, uu * B4.y);
        dA = exp2f(dt * a2.z); h2 = fmaf(dA, h2, uu * B4.z);
        dA = exp2f(dt * a2.w); h3 = fmaf(dA, h3, uu * B4.w);
        float p = fmaf(h3, C4.w, fmaf(h2, C4.z, fmaf(h1, C4.y, h0 * C4.x)));
        p += __shfl_xor(p, 16);
        p += __shfl_xor(p, 32);
        if (nq == 0) op[(size_t)i * DM] = fmaf(xv, Dv, p);
    }
}

extern "C" void kernel_launch(void* const* d_in, const int* in_sizes, int n_in,
                              void* d_out, int out_size, void* d_ws, size_t ws_size,
                              hipStream_t stream) {
    const float* x      = (const float*)d_in[0];
    const float* A_log  = (const float*)d_in[1];
    const float* Dvec   = (const float*)d_in[2];
    const float* Wx     = (const float*)d_in[3];
    const float* Wdt    = (const float*)d_in[4];
    const float* dtb    = (const float*)d_in[5];
    const float* convw  = (const float*)d_in[6];
    const float* convb  = (const float*)d_in[7];
    float* out = (float*)d_out;
    float* wsf = (float*)d_ws;

    uint32_t* dx    = (uint32_t*)(wsf + WS_DX);
    float*    xdbl  = wsf + WS_XDBL;
    float*    WxT   = wsf + WS_WXT;
    float*    WdtT  = wsf + WS_WDTT;
    float*    A2    = wsf + WS_A2;
    float*    dtsum = wsf + WS_DTSUM;
    float*    S     = wsf + WS_S;

    k_prep<<<128, 256, 0, stream>>>(Wx, Wdt, A_log, WxT, WdtT, A2);
    k_front<<<1024, 256, 0, stream>>>(x, convw, convb, WxT, WdtT, dtb, dx, xdbl);
    k_scan1<<<1024, 256, 0, stream>>>(dx, xdbl, A2, S, dtsum);
    k_scan23<<<1024, 256, 0, stream>>>(dx, xdbl, A2, Dvec, S, dtsum, out);
}

// Round 12
// 126.662 us; speedup vs baseline: 4.4455x; 1.0344x over previous
//
#include <hip/hip_runtime.h>
#include <stdint.h>

#define L_SEQ   2048
#define NBATCH  4
#define DM      512
#define DS      16
#define DR      32
#define NBDN    32768         // NBATCH*DM*DS chains
#define NCH     32            // chunks
#define CL      64            // chunk length
#define LOG2E   1.4426950408889634f

// ws layout (float offsets)
#define WS_DX    0            // 4194304  packed (bf16 dt | bf16 xc) [b,l][d]
#define WS_XDBL  4194304      // 524288   x_dbl [row][64] (dt-raw | B | C) f32
#define WS_WXT   4718592      // 32768    WxT[d][j]
#define WS_WDTT  4751360      // 16384    WdtT[r][d]
#define WS_A2    4767744      // 8192     A2[d][n] = -exp(A_log)*log2e
#define WS_DTSUM 4775936      // 65536    dtsum[c][b*DM+d]
#define WS_S     4841472      // 1048576  S[c][chain]; scan2 rewrites in-place to Hin
// total 5890048 floats = 23.6 MB

__device__ __forceinline__ uint32_t bf16_rne_hi(float v) {   // bf16 in high 16 bits
    uint32_t u = __float_as_uint(v);
    u += 0x7FFF + ((u >> 16) & 1);
    return u & 0xFFFF0000u;
}
__device__ __forceinline__ float bf_lo(uint32_t u) { return __uint_as_float(u << 16); }
__device__ __forceinline__ float bf_hi(uint32_t u) { return __uint_as_float(u & 0xFFFF0000u); }
// pack two floats as (bf16(b)<<16 | bf16(a))
__device__ __forceinline__ uint32_t pack2(float a, float b) {
    return bf16_rne_hi(b) | (bf16_rne_hi(a) >> 16);
}

// ---------------- prep: weight transposes + A2 ----------------
__global__ void __launch_bounds__(256) k_prep(
        const float* __restrict__ Wx, const float* __restrict__ Wdt,
        const float* __restrict__ A_log, float* __restrict__ WxT,
        float* __restrict__ WdtT, float* __restrict__ A2) {
    int idx = blockIdx.x * 256 + threadIdx.x;
    if (idx < DM * 64) {                 // WxT[d][j] = Wx[j][d]
        int dd = idx >> 6, j = idx & 63;
        WxT[idx] = Wx[j * DM + dd];
    }
    if (idx < DR * DM) {                 // WdtT[r][d] = Wdt[d][r]
        int r = idx >> 9, dd = idx & 511;
        WdtT[idx] = Wdt[dd * DR + r];
    }
    if (idx < DM * DS)
        A2[idx] = -__expf(A_log[idx]) * LOG2E;
}

// ---------------- front: conv + proj1 (bf16 LDS) + proj2 + bf16 pack ----------------
// 1024 blocks x 256 threads; block = 8 consecutive rows.
__global__ void __launch_bounds__(256) k_front(
        const float* __restrict__ x, const float* __restrict__ convw,
        const float* __restrict__ convb, const float* __restrict__ WxT,
        const float* __restrict__ WdtT, const float* __restrict__ dtb,
        uint32_t* __restrict__ dx, float* __restrict__ xdbl) {
    __shared__ uint32_t xcs2[8][256];  // conv output, packed bf16 pairs (k-major)
    __shared__ float pt[4][8][64];     // per-wave K-split partials
    __shared__ float xds[8][64];       // reduced x_dbl rows
    int t  = threadIdx.x;
    int r0 = blockIdx.x * 8;
    int b  = r0 >> 11, l0 = r0 & (L_SEQ - 1);
    int dq = t & 127, half = t >> 7;

    // ---- conv (f32 math, bf16-pack the result) ----
    {
        const float4* wp = (const float4*)convw;
        float4 w0 = wp[dq * 4 + 0], w1 = wp[dq * 4 + 1];
        float4 w2 = wp[dq * 4 + 2], w3 = wp[dq * 4 + 3];
        float4 bias = ((const float4*)convb)[dq];
        #pragma unroll
        for (int i = 0; i < 4; ++i) {
            int row = half * 4 + i;
            int l   = l0 + row;
            const float* xr = x + ((size_t)(b * L_SEQ + l)) * DM + dq * 4;
            float4 acc = bias;
            float4 xv = *(const float4*)xr;
            acc.x = fmaf(xv.x, w0.w, acc.x); acc.y = fmaf(xv.y, w1.w, acc.y);
            acc.z = fmaf(xv.z, w2.w, acc.z); acc.w = fmaf(xv.w, w3.w, acc.w);
            if (l >= 1) {
                xv = *(const float4*)(xr - DM);
                acc.x = fmaf(xv.x, w0.z, acc.x); acc.y = fmaf(xv.y, w1.z, acc.y);
                acc.z = fmaf(xv.z, w2.z, acc.z); acc.w = fmaf(xv.w, w3.z, acc.w);
            }
            if (l >= 2) {
                xv = *(const float4*)(xr - 2 * DM);
                acc.x = fmaf(xv.x, w0.y, acc.x); acc.y = fmaf(xv.y, w1.y, acc.y);
                acc.z = fmaf(xv.z, w2.y, acc.z); acc.w = fmaf(xv.w, w3.y, acc.w);
            }
            if (l >= 3) {
                xv = *(const float4*)(xr - 3 * DM);
                acc.x = fmaf(xv.x, w0.x, acc.x); acc.y = fmaf(xv.y, w1.x, acc.y);
                acc.z = fmaf(xv.z, w2.x, acc.z); acc.w = fmaf(xv.w, w3.x, acc.w);
            }
            uint2 pk;
            pk.x = pack2(acc.x, acc.y);
            pk.y = pack2(acc.z, acc.w);
            *(uint2*)(&xcs2[row][dq * 2]) = pk;
        }
    }
    __syncthreads();

    // ---- proj1: wave wv owns K-slice [wv*128, wv*128+128); bf16 xc from LDS ----
    {
        int wv = t >> 6, j = t & 63;
        int k0 = wv * 128;
        float acc[8] = {0.f, 0.f, 0.f, 0.f, 0.f, 0.f, 0.f, 0.f};
        const float* wp = WxT + (size_t)k0 * 64 + j;
        for (int kc = 0; kc < 16; ++kc) {          // 8 k-values per iteration
            float w[8];
            #pragma unroll
            for (int kk = 0; kk < 8; ++kk)
                w[kk] = wp[(kc * 8 + kk) * 64];
            #pragma unroll
            for (int ri = 0; ri < 8; ++ri) {
                uint4 X = *(const uint4*)(&xcs2[ri][wv * 64 + kc * 4]);  // wave-uniform
                acc[ri] = fmaf(bf_lo(X.x), w[0], acc[ri]);
                acc[ri] = fmaf(bf_hi(X.x), w[1], acc[ri]);
                acc[ri] = fmaf(bf_lo(X.y), w[2], acc[ri]);
                acc[ri] = fmaf(bf_hi(X.y), w[3], acc[ri]);
                acc[ri] = fmaf(bf_lo(X.z), w[4], acc[ri]);
                acc[ri] = fmaf(bf_hi(X.z), w[5], acc[ri]);
                acc[ri] = fmaf(bf_lo(X.w), w[6], acc[ri]);
                acc[ri] = fmaf(bf_hi(X.w), w[7], acc[ri]);
            }
        }
        #pragma unroll
        for (int ri = 0; ri < 8; ++ri) pt[wv][ri][j] = acc[ri];
    }
    __syncthreads();

    // ---- reduce K-slices -> xds + global xdbl ----
    #pragma unroll
    for (int o = t; o < 512; o += 256) {
        int row = o >> 6, j2 = o & 63;
        float s = (pt[0][row][j2] + pt[1][row][j2])
                + (pt[2][row][j2] + pt[3][row][j2]);
        xds[row][j2] = s;
        xdbl[(size_t)(r0 + row) * 64 + j2] = s;
    }
    __syncthreads();

    // ---- proj2 + softplus + pack (dt|xc) bf16 ----
    {
        float4 bias = ((const float4*)dtb)[dq];
        float4 z0 = bias, z1 = bias, z2 = bias, z3 = bias;
        for (int r = 0; r < DR; ++r) {
            float4 w4 = *(const float4*)(WdtT + r * DM + dq * 4);
            float x0 = xds[half * 4 + 0][r];
            float x1 = xds[half * 4 + 1][r];
            float x2 = xds[half * 4 + 2][r];
            float x3 = xds[half * 4 + 3][r];
            z0.x = fmaf(x0, w4.x, z0.x); z0.y = fmaf(x0, w4.y, z0.y);
            z0.z = fmaf(x0, w4.z, z0.z); z0.w = fmaf(x0, w4.w, z0.w);
            z1.x = fmaf(x1, w4.x, z1.x); z1.y = fmaf(x1, w4.y, z1.y);
            z1.z = fmaf(x1, w4.z, z1.z); z1.w = fmaf(x1, w4.w, z1.w);
            z2.x = fmaf(x2, w4.x, z2.x); z2.y = fmaf(x2, w4.y, z2.y);
            z2.z = fmaf(x2, w4.z, z2.z); z2.w = fmaf(x2, w4.w, z2.w);
            z3.x = fmaf(x3, w4.x, z3.x); z3.y = fmaf(x3, w4.y, z3.y);
            z3.z = fmaf(x3, w4.z, z3.z); z3.w = fmaf(x3, w4.w, z3.w);
        }
        float4 zz[4] = {z0, z1, z2, z3};
        #pragma unroll
        for (int i = 0; i < 4; ++i) {
            int row = half * 4 + i;
            float4 zi = zz[i];
            float4 sp;
            sp.x = fmaxf(zi.x, 0.f) + log1pf(__expf(-fabsf(zi.x)));
            sp.y = fmaxf(zi.y, 0.f) + log1pf(__expf(-fabsf(zi.y)));
            sp.z = fmaxf(zi.z, 0.f) + log1pf(__expf(-fabsf(zi.z)));
            sp.w = fmaxf(zi.w, 0.f) + log1pf(__expf(-fabsf(zi.w)));
            uint2 xc2 = *(const uint2*)(&xcs2[row][dq * 2]);   // bf16 bits of xc
            uint4 pk;
            pk.x = bf16_rne_hi(sp.x) | (xc2.x & 0xFFFFu);
            pk.y = bf16_rne_hi(sp.y) | (xc2.x >> 16);
            pk.z = bf16_rne_hi(sp.z) | (xc2.y & 0xFFFFu);
            pk.w = bf16_rne_hi(sp.w) | (xc2.y >> 16);
            *(uint4*)(dx + ((size_t)(b * L_SEQ + l0 + row)) * DM + dq * 4) = pk;
        }
    }
}

// ---------------- scan1: per-chunk local scan -> S, dtsum ----------------
__global__ void __launch_bounds__(256) k_scan1(
        const uint32_t* __restrict__ dx, const float* __restrict__ xdbl,
        const float* __restrict__ A2, float* __restrict__ S,
        float* __restrict__ dtsum) {
    int t      = threadIdx.x;
    int u      = blockIdx.x;
    int lane   = t & 63;
    int wv     = t >> 6;
    int dlocal = lane & 15;
    int nq     = lane >> 4;
    int db8    = u & 7;
    int c      = (u >> 3) & (NCH - 1);
    int b      = u >> 8;
    int d      = (db8 * 4 + wv) * 16 + dlocal;
    int l0     = c * CL;

    float4 a2 = *(const float4*)(A2 + (size_t)d * DS + nq * 4);
    float h0 = 0.f, h1 = 0.f, h2 = 0.f, h3 = 0.f;
    float dsum = 0.f;
    const uint32_t* dxp = dx + ((size_t)(b * L_SEQ + l0)) * DM + d;
    const float*    bp  = xdbl + ((size_t)(b * L_SEQ + l0)) * 64 + DR + nq * 4;

    #pragma unroll 8
    for (int i = 0; i < CL; ++i) {
        uint32_t v = dxp[(size_t)i * DM];
        float dt = bf_hi(v);
        float xv = bf_lo(v);
        float4 B4 = *(const float4*)(bp + (size_t)i * 64);
        float uu = dt * xv;
        dsum += dt;
        float dA;
        dA = exp2f(dt * a2.x); h0 = fmaf(dA, h0, uu * B4.x);
        dA = exp2f(dt * a2.y); h1 = fmaf(dA, h1, uu * B4.y);
        dA = exp2f(dt * a2.z); h2 = fmaf(dA, h2, uu * B4.z);
        dA = exp2f(dt * a2.w); h3 = fmaf(dA, h3, uu * B4.w);
    }
    float4 sv; sv.x = h0; sv.y = h1; sv.z = h2; sv.w = h3;
    *(float4*)(S + (size_t)c * NBDN + ((size_t)(b * DM + d)) * DS + nq * 4) = sv;
    if (nq == 0)
        dtsum[c * (NBATCH * DM) + b * DM + d] = dsum;
}

// ---------------- scan2: cross-chunk prefix; P from dtsum telescope; in-place Hin ----------------
__global__ void __launch_bounds__(256) k_scan2(
        const float* __restrict__ dtsum, const float* __restrict__ A2,
        float* __restrict__ S) {
    int t  = blockIdx.x * 256 + threadIdx.x;       // 0..32767
    float a2 = A2[t & (DM * DS - 1)];
    int bd = t >> 4;                               // b*DM+d
    float H = 0.f;
    #pragma unroll 8
    for (int cc = 0; cc < NCH; ++cc) {
        float p = exp2f(a2 * dtsum[cc * (NBATCH * DM) + bd]);
        float s = S[(size_t)cc * NBDN + t];
        S[(size_t)cc * NBDN + t] = H;              // Hin for chunk cc
        H = fmaf(p, H, s);
    }
}

// ---------------- scan3: replay chunk from Hin, emit y ----------------
__global__ void __launch_bounds__(256) k_scan3(
        const uint32_t* __restrict__ dx, const float* __restrict__ xdbl,
        const float* __restrict__ A2, const float* __restrict__ Dvec,
        const float* __restrict__ Hin, float* __restrict__ out) {
    int t      = threadIdx.x;
    int u      = blockIdx.x;
    int lane   = t & 63;
    int wv     = t >> 6;
    int dlocal = lane & 15;
    int nq     = lane >> 4;
    int db8    = u & 7;
    int c      = (u >> 3) & (NCH - 1);
    int b      = u >> 8;
    int d      = (db8 * 4 + wv) * 16 + dlocal;
    int l0     = c * CL;

    float4 a2 = *(const float4*)(A2 + (size_t)d * DS + nq * 4);
    float Dv = Dvec[d];
    float4 hv = *(const float4*)(Hin + (size_t)c * NBDN + ((size_t)(b * DM + d)) * DS + nq * 4);
    float h0 = hv.x, h1 = hv.y, h2 = hv.z, h3 = hv.w;

    const uint32_t* dxp = dx + ((size_t)(b * L_SEQ + l0)) * DM + d;
    const float*    bp  = xdbl + ((size_t)(b * L_SEQ + l0)) * 64 + DR + nq * 4;
    float* op = out + ((size_t)(b * L_SEQ + l0)) * DM + d;

    #pragma unroll 8
    for (int i = 0; i < CL; ++i) {
        uint32_t v = dxp[(size_t)i * DM];
        float dt = bf_hi(v);
        float xv = bf_lo(v);
        float4 B4 = *(const float4*)(bp + (size_t)i * 64);
        float4 C4 = *(const float4*)(bp + (size_t)i * 64 + DS);
        float uu = dt * xv;
        float dA;
        dA = exp2f(dt * a2.x); h0 = fmaf(dA, h0, uu * B4.x);
        dA = exp2f(dt * a2.y); h1 = fmaf(dA, h1, uu * B4.y);
        dA = exp2f(dt * a2.z); h2 = fmaf(dA, h2, uu * B4.z);
        dA = exp2f(dt * a2.w); h3 = fmaf(dA, h3, uu * B4.w);
        float p = fmaf(h3, C4.w, fmaf(h2, C4.z, fmaf(h1, C4.y, h0 * C4.x)));
        p += __shfl_xor(p, 16);
        p += __shfl_xor(p, 32);
        if (nq == 0) op[(size_t)i * DM] = fmaf(xv, Dv, p);
    }
}

extern "C" void kernel_launch(void* const* d_in, const int* in_sizes, int n_in,
                              void* d_out, int out_size, void* d_ws, size_t ws_size,
                              hipStream_t stream) {
    const float* x      = (const float*)d_in[0];
    const float* A_log  = (const float*)d_in[1];
    const float* Dvec   = (const float*)d_in[2];
    const float* Wx     = (const float*)d_in[3];
    const float* Wdt    = (const float*)d_in[4];
    const float* dtb    = (const float*)d_in[5];
    const float* convw  = (const float*)d_in[6];
    const float* convb  = (const float*)d_in[7];
    float* out = (float*)d_out;
    float* wsf = (float*)d_ws;

    uint32_t* dx    = (uint32_t*)(wsf + WS_DX);
    float*    xdbl  = wsf + WS_XDBL;
    float*    WxT   = wsf + WS_WXT;
    float*    WdtT  = wsf + WS_WDTT;
    float*    A2    = wsf + WS_A2;
    float*    dtsum = wsf + WS_DTSUM;
    float*    S     = wsf + WS_S;

    k_prep<<<128, 256, 0, stream>>>(Wx, Wdt, A_log, WxT, WdtT, A2);
    k_front<<<1024, 256, 0, stream>>>(x, convw, convb, WxT, WdtT, dtb, dx, xdbl);
    k_scan1<<<1024, 256, 0, stream>>>(dx, xdbl, A2, S, dtsum);
    k_scan2<<<128, 256, 0, stream>>>(dtsum, A2, S);
    k_scan3<<<1024, 256, 0, stream>>>(dx, xdbl, A2, Dvec, S, out);
}

// Round 13
// 103.769 us; speedup vs baseline: 5.4262x; 1.2206x over previous
//
#include <hip/hip_runtime.h>
#include <stdint.h>

#define L_SEQ   2048
#define NBATCH  4
#define DM      512
#define DS      16
#define DR      32
#define NBDN    32768         // NBATCH*DM*DS chains
#define NCH     64            // chunks  (R8-proven geometry)
#define CL      32            // chunk length
#define LOG2E   1.4426950408889634f

// ws layout (float offsets)
#define WS_DX    0            // 4194304  packed (bf16 dt | bf16 xc) [b,l][d]
#define WS_XDBL  4194304      // 524288   x_dbl [row][64] (dt-raw | B | C) f32
#define WS_WXT   4718592      // 32768    WxT[d][j]
#define WS_WDTT  4751360      // 16384    WdtT[r][d]
#define WS_A2    4767744      // 8192     A2[d][n] = -exp(A_log)*log2e
#define WS_DTSUM 4775936      // 131072   dtsum[c][b*DM+d]
#define WS_S     4907008      // 2097152  S[c][chain]; scan2 rewrites in-place to Hin
// total 7004160 floats = 28.0 MB

__device__ __forceinline__ uint32_t bf16_rne_hi(float v) {   // bf16 in high 16 bits
    uint32_t u = __float_as_uint(v);
    u += 0x7FFF + ((u >> 16) & 1);
    return u & 0xFFFF0000u;
}
__device__ __forceinline__ float bf_lo(uint32_t u) { return __uint_as_float(u << 16); }
__device__ __forceinline__ float bf_hi(uint32_t u) { return __uint_as_float(u & 0xFFFF0000u); }
__device__ __forceinline__ uint32_t pack2(float a, float b) {   // (bf16(b)<<16 | bf16(a))
    return bf16_rne_hi(b) | (bf16_rne_hi(a) >> 16);
}

// ---------------- prep: weight transposes + A2 ----------------
__global__ void __launch_bounds__(256) k_prep(
        const float* __restrict__ Wx, const float* __restrict__ Wdt,
        const float* __restrict__ A_log, float* __restrict__ WxT,
        float* __restrict__ WdtT, float* __restrict__ A2) {
    int idx = blockIdx.x * 256 + threadIdx.x;
    if (idx < DM * 64) {                 // WxT[d][j] = Wx[j][d]
        int dd = idx >> 6, j = idx & 63;
        WxT[idx] = Wx[j * DM + dd];
    }
    if (idx < DR * DM) {                 // WdtT[r][d] = Wdt[d][r]
        int r = idx >> 9, dd = idx & 511;
        WdtT[idx] = Wdt[dd * DR + r];
    }
    if (idx < DM * DS)
        A2[idx] = -__expf(A_log[idx]) * LOG2E;
}

// ---------------- front: conv + proj1 (bf16 LDS) + proj2 + bf16 pack ----------------
// 1024 blocks x 256 threads; block = 8 consecutive rows.
__global__ void __launch_bounds__(256) k_front(
        const float* __restrict__ x, const float* __restrict__ convw,
        const float* __restrict__ convb, const float* __restrict__ WxT,
        const float* __restrict__ WdtT, const float* __restrict__ dtb,
        uint32_t* __restrict__ dx, float* __restrict__ xdbl) {
    __shared__ uint32_t xcs2[8][256];  // conv output, packed bf16 pairs (k-major)
    __shared__ float pt[4][8][64];     // per-wave K-split partials
    __shared__ float xds[8][64];       // reduced x_dbl rows
    int t  = threadIdx.x;
    int r0 = blockIdx.x * 8;
    int b  = r0 >> 11, l0 = r0 & (L_SEQ - 1);
    int dq = t & 127, half = t >> 7;

    // ---- conv (f32 math, bf16-pack the result) ----
    {
        const float4* wp = (const float4*)convw;
        float4 w0 = wp[dq * 4 + 0], w1 = wp[dq * 4 + 1];
        float4 w2 = wp[dq * 4 + 2], w3 = wp[dq * 4 + 3];
        float4 bias = ((const float4*)convb)[dq];
        #pragma unroll
        for (int i = 0; i < 4; ++i) {
            int row = half * 4 + i;
            int l   = l0 + row;
            const float* xr = x + ((size_t)(b * L_SEQ + l)) * DM + dq * 4;
            float4 acc = bias;
            float4 xv = *(const float4*)xr;
            acc.x = fmaf(xv.x, w0.w, acc.x); acc.y = fmaf(xv.y, w1.w, acc.y);
            acc.z = fmaf(xv.z, w2.w, acc.z); acc.w = fmaf(xv.w, w3.w, acc.w);
            if (l >= 1) {
                xv = *(const float4*)(xr - DM);
                acc.x = fmaf(xv.x, w0.z, acc.x); acc.y = fmaf(xv.y, w1.z, acc.y);
                acc.z = fmaf(xv.z, w2.z, acc.z); acc.w = fmaf(xv.w, w3.z, acc.w);
            }
            if (l >= 2) {
                xv = *(const float4*)(xr - 2 * DM);
                acc.x = fmaf(xv.x, w0.y, acc.x); acc.y = fmaf(xv.y, w1.y, acc.y);
                acc.z = fmaf(xv.z, w2.y, acc.z); acc.w = fmaf(xv.w, w3.y, acc.w);
            }
            if (l >= 3) {
                xv = *(const float4*)(xr - 3 * DM);
                acc.x = fmaf(xv.x, w0.x, acc.x); acc.y = fmaf(xv.y, w1.x, acc.y);
                acc.z = fmaf(xv.z, w2.x, acc.z); acc.w = fmaf(xv.w, w3.x, acc.w);
            }
            uint2 pk;
            pk.x = pack2(acc.x, acc.y);
            pk.y = pack2(acc.z, acc.w);
            *(uint2*)(&xcs2[row][dq * 2]) = pk;
        }
    }
    __syncthreads();

    // ---- proj1: wave wv owns K-slice [wv*128, wv*128+128); bf16 xc from LDS ----
    {
        int wv = t >> 6, j = t & 63;
        int k0 = wv * 128;
        float acc[8] = {0.f, 0.f, 0.f, 0.f, 0.f, 0.f, 0.f, 0.f};
        const float* wp = WxT + (size_t)k0 * 64 + j;
        for (int kc = 0; kc < 16; ++kc) {          // 8 k-values per iteration
            float w[8];
            #pragma unroll
            for (int kk = 0; kk < 8; ++kk)
                w[kk] = wp[(kc * 8 + kk) * 64];
            #pragma unroll
            for (int ri = 0; ri < 8; ++ri) {
                uint4 X = *(const uint4*)(&xcs2[ri][wv * 64 + kc * 4]);  // wave-uniform
                acc[ri] = fmaf(bf_lo(X.x), w[0], acc[ri]);
                acc[ri] = fmaf(bf_hi(X.x), w[1], acc[ri]);
                acc[ri] = fmaf(bf_lo(X.y), w[2], acc[ri]);
                acc[ri] = fmaf(bf_hi(X.y), w[3], acc[ri]);
                acc[ri] = fmaf(bf_lo(X.z), w[4], acc[ri]);
                acc[ri] = fmaf(bf_hi(X.z), w[5], acc[ri]);
                acc[ri] = fmaf(bf_lo(X.w), w[6], acc[ri]);
                acc[ri] = fmaf(bf_hi(X.w), w[7], acc[ri]);
            }
        }
        #pragma unroll
        for (int ri = 0; ri < 8; ++ri) pt[wv][ri][j] = acc[ri];
    }
    __syncthreads();

    // ---- reduce K-slices -> xds + global xdbl ----
    #pragma unroll
    for (int o = t; o < 512; o += 256) {
        int row = o >> 6, j2 = o & 63;
        float s = (pt[0][row][j2] + pt[1][row][j2])
                + (pt[2][row][j2] + pt[3][row][j2]);
        xds[row][j2] = s;
        xdbl[(size_t)(r0 + row) * 64 + j2] = s;
    }
    __syncthreads();

    // ---- proj2 + softplus + pack (dt|xc) bf16 ----
    {
        float4 bias = ((const float4*)dtb)[dq];
        float4 z0 = bias, z1 = bias, z2 = bias, z3 = bias;
        for (int r = 0; r < DR; ++r) {
            float4 w4 = *(const float4*)(WdtT + r * DM + dq * 4);
            float x0 = xds[half * 4 + 0][r];
            float x1 = xds[half * 4 + 1][r];
            float x2 = xds[half * 4 + 2][r];
            float x3 = xds[half * 4 + 3][r];
            z0.x = fmaf(x0, w4.x, z0.x); z0.y = fmaf(x0, w4.y, z0.y);
            z0.z = fmaf(x0, w4.z, z0.z); z0.w = fmaf(x0, w4.w, z0.w);
            z1.x = fmaf(x1, w4.x, z1.x); z1.y = fmaf(x1, w4.y, z1.y);
            z1.z = fmaf(x1, w4.z, z1.z); z1.w = fmaf(x1, w4.w, z1.w);
            z2.x = fmaf(x2, w4.x, z2.x); z2.y = fmaf(x2, w4.y, z2.y);
            z2.z = fmaf(x2, w4.z, z2.z); z2.w = fmaf(x2, w4.w, z2.w);
            z3.x = fmaf(x3, w4.x, z3.x); z3.y = fmaf(x3, w4.y, z3.y);
            z3.z = fmaf(x3, w4.z, z3.z); z3.w = fmaf(x3, w4.w, z3.w);
        }
        float4 zz[4] = {z0, z1, z2, z3};
        #pragma unroll
        for (int i = 0; i < 4; ++i) {
            int row = half * 4 + i;
            float4 zi = zz[i];
            float4 sp;
            sp.x = fmaxf(zi.x, 0.f) + log1pf(__expf(-fabsf(zi.x)));
            sp.y = fmaxf(zi.y, 0.f) + log1pf(__expf(-fabsf(zi.y)));
            sp.z = fmaxf(zi.z, 0.f) + log1pf(__expf(-fabsf(zi.z)));
            sp.w = fmaxf(zi.w, 0.f) + log1pf(__expf(-fabsf(zi.w)));
            uint2 xc2 = *(const uint2*)(&xcs2[row][dq * 2]);   // bf16 bits of xc
            uint4 pk;
            pk.x = bf16_rne_hi(sp.x) | (xc2.x & 0xFFFFu);
            pk.y = bf16_rne_hi(sp.y) | (xc2.x >> 16);
            pk.z = bf16_rne_hi(sp.z) | (xc2.y & 0xFFFFu);
            pk.w = bf16_rne_hi(sp.w) | (xc2.y >> 16);
            *(uint4*)(dx + ((size_t)(b * L_SEQ + l0 + row)) * DM + dq * 4) = pk;
        }
    }
}

// ---------------- scan1: per-chunk local scan -> S, dtsum ----------------
// grid dim3(512, 4): x = db8(3) | c(6); y = b.  2048 blocks -> 8 waves/SIMD.
__global__ void __launch_bounds__(256) k_scan1(
        const uint32_t* __restrict__ dx, const float* __restrict__ xdbl,
        const float* __restrict__ A2, float* __restrict__ S,
        float* __restrict__ dtsum) {
    int t      = threadIdx.x;
    int lane   = t & 63;
    int wv     = t >> 6;
    int dlocal = lane & 15;
    int nq     = lane >> 4;
    int db8    = blockIdx.x & 7;
    int c      = blockIdx.x >> 3;
    int b      = blockIdx.y;
    int d      = (db8 * 4 + wv) * 16 + dlocal;
    int l0     = c * CL;

    float4 a2 = *(const float4*)(A2 + (size_t)d * DS + nq * 4);
    float h0 = 0.f, h1 = 0.f, h2 = 0.f, h3 = 0.f;
    float dsum = 0.f;
    const uint32_t* dxp = dx + ((size_t)(b * L_SEQ + l0)) * DM + d;
    const float*    bp  = xdbl + ((size_t)(b * L_SEQ + l0)) * 64 + DR + nq * 4;

    #pragma unroll 8
    for (int i = 0; i < CL; ++i) {
        uint32_t v = dxp[(size_t)i * DM];
        float dt = bf_hi(v);
        float xv = bf_lo(v);
        float4 B4 = *(const float4*)(bp + (size_t)i * 64);
        float uu = dt * xv;
        dsum += dt;
        float dA;
        dA = exp2f(dt * a2.x); h0 = fmaf(dA, h0, uu * B4.x);
        dA = exp2f(dt * a2.y); h1 = fmaf(dA, h1, uu * B4.y);
        dA = exp2f(dt * a2.z); h2 = fmaf(dA, h2, uu * B4.z);
        dA = exp2f(dt * a2.w); h3 = fmaf(dA, h3, uu * B4.w);
    }
    float4 sv; sv.x = h0; sv.y = h1; sv.z = h2; sv.w = h3;
    *(float4*)(S + (size_t)c * NBDN + ((size_t)(b * DM + d)) * DS + nq * 4) = sv;
    if (nq == 0)
        dtsum[c * (NBATCH * DM) + b * DM + d] = dsum;
}

// ---------------- scan2: cross-chunk prefix; P from dtsum telescope; in-place Hin ----------------
__global__ void __launch_bounds__(256) k_scan2(
        const float* __restrict__ dtsum, const float* __restrict__ A2,
        float* __restrict__ S) {
    int t  = blockIdx.x * 256 + threadIdx.x;       // 0..32767
    float a2 = A2[t & (DM * DS - 1)];
    int bd = t >> 4;                               // b*DM+d
    float H = 0.f;
    #pragma unroll 8
    for (int cc = 0; cc < NCH; ++cc) {
        float p = exp2f(a2 * dtsum[cc * (NBATCH * DM) + bd]);
        float s = S[(size_t)cc * NBDN + t];
        S[(size_t)cc * NBDN + t] = H;              // Hin for chunk cc
        H = fmaf(p, H, s);
    }
}

// ---------------- scan3: replay chunk from Hin, emit y ----------------
__global__ void __launch_bounds__(256) k_scan3(
        const uint32_t* __restrict__ dx, const float* __restrict__ xdbl,
        const float* __restrict__ A2, const float* __restrict__ Dvec,
        const float* __restrict__ Hin, float* __restrict__ out) {
    int t      = threadIdx.x;
    int lane   = t & 63;
    int wv     = t >> 6;
    int dlocal = lane & 15;
    int nq     = lane >> 4;
    int db8    = blockIdx.x & 7;
    int c      = blockIdx.x >> 3;
    int b      = blockIdx.y;
    int d      = (db8 * 4 + wv) * 16 + dlocal;
    int l0     = c * CL;

    float4 a2 = *(const float4*)(A2 + (size_t)d * DS + nq * 4);
    float Dv = Dvec[d];
    float4 hv = *(const float4*)(Hin + (size_t)c * NBDN + ((size_t)(b * DM + d)) * DS + nq * 4);
    float h0 = hv.x, h1 = hv.y, h2 = hv.z, h3 = hv.w;

    const uint32_t* dxp = dx + ((size_t)(b * L_SEQ + l0)) * DM + d;
    const float*    bp  = xdbl + ((size_t)(b * L_SEQ + l0)) * 64 + DR + nq * 4;
    float* op = out + ((size_t)(b * L_SEQ + l0)) * DM + d;

    #pragma unroll 8
    for (int i = 0; i < CL; ++i) {
        uint32_t v = dxp[(size_t)i * DM];
        float dt = bf_hi(v);
        float xv = bf_lo(v);
        float4 B4 = *(const float4*)(bp + (size_t)i * 64);
        float4 C4 = *(const float4*)(bp + (size_t)i * 64 + DS);
        float uu = dt * xv;
        float dA;
        dA = exp2f(dt * a2.x); h0 = fmaf(dA, h0, uu * B4.x);
        dA = exp2f(dt * a2.y); h1 = fmaf(dA, h1, uu * B4.y);
        dA = exp2f(dt * a2.z); h2 = fmaf(dA, h2, uu * B4.z);
        dA = exp2f(dt * a2.w); h3 = fmaf(dA, h3, uu * B4.w);
        float p = fmaf(h3, C4.w, fmaf(h2, C4.z, fmaf(h1, C4.y, h0 * C4.x)));
        p += __shfl_xor(p, 16);
        p += __shfl_xor(p, 32);
        if (nq == 0) op[(size_t)i * DM] = fmaf(xv, Dv, p);
    }
}

extern "C" void kernel_launch(void* const* d_in, const int* in_sizes, int n_in,
                              void* d_out, int out_size, void* d_ws, size_t ws_size,
                              hipStream_t stream) {
    const float* x      = (const float*)d_in[0];
    const float* A_log  = (const float*)d_in[1];
    const float* Dvec   = (const float*)d_in[2];
    const float* Wx     = (const float*)d_in[3];
    const float* Wdt    = (const float*)d_in[4];
    const float* dtb    = (const float*)d_in[5];
    const float* convw  = (const float*)d_in[6];
    const float* convb  = (const float*)d_in[7];
    float* out = (float*)d_out;
    float* wsf = (float*)d_ws;

    uint32_t* dx    = (uint32_t*)(wsf + WS_DX);
    float*    xdbl  = wsf + WS_XDBL;
    float*    WxT   = wsf + WS_WXT;
    float*    WdtT  = wsf + WS_WDTT;
    float*    A2    = wsf + WS_A2;
    float*    dtsum = wsf + WS_DTSUM;
    float*    S     = wsf + WS_S;

    k_prep<<<128, 256, 0, stream>>>(Wx, Wdt, A_log, WxT, WdtT, A2);
    k_front<<<1024, 256, 0, stream>>>(x, convw, convb, WxT, WdtT, dtb, dx, xdbl);
    k_scan1<<<dim3(512, 4), 256, 0, stream>>>(dx, xdbl, A2, S, dtsum);
    k_scan2<<<128, 256, 0, stream>>>(dtsum, A2, S);
    k_scan3<<<dim3(512, 4), 256, 0, stream>>>(dx, xdbl, A2, Dvec, S, out);
}

// Round 14
// 100.918 us; speedup vs baseline: 5.5795x; 1.0283x over previous
//
#include <hip/hip_runtime.h>
#include <stdint.h>

#define L_SEQ   2048
#define NBATCH  4
#define DM      512
#define DS      16
#define DR      32
#define NBDN    32768         // NBATCH*DM*DS chains
#define NCH     64            // chunks  (R8-proven geometry)
#define CL      32            // chunk length
#define LOG2E   1.4426950408889634f

// ws layout (float offsets)
#define WS_DX    0            // 4194304  packed (bf16 dt | bf16 xc) [b,l][d]
#define WS_XDBL  4194304      // 524288   x_dbl [row][64] (dt-raw | B | C) f32
#define WS_WXT   4718592      // 32768    WxT[k][j]
#define WS_WDTT  4751360      // 16384    WdtT[r][d]
#define WS_A2    4767744      // 8192     A2[d][n] = -exp(A_log)*log2e
#define WS_DTSUM 4775936      // 131072   dtsum[c][b*DM+d]
#define WS_S     4907008      // 2097152  S[c][chain]; scan2 rewrites in-place to Hin
// total 7004160 floats = 28.0 MB

__device__ __forceinline__ uint32_t bf16_rne_hi(float v) {   // bf16 in high 16 bits
    uint32_t u = __float_as_uint(v);
    u += 0x7FFF + ((u >> 16) & 1);
    return u & 0xFFFF0000u;
}
__device__ __forceinline__ float bf_lo(uint32_t u) { return __uint_as_float(u << 16); }
__device__ __forceinline__ float bf_hi(uint32_t u) { return __uint_as_float(u & 0xFFFF0000u); }

// ---------------- prep: weight transposes + A2 ----------------
__global__ void __launch_bounds__(256) k_prep(
        const float* __restrict__ Wx, const float* __restrict__ Wdt,
        const float* __restrict__ A_log, float* __restrict__ WxT,
        float* __restrict__ WdtT, float* __restrict__ A2) {
    int idx = blockIdx.x * 256 + threadIdx.x;
    if (idx < DM * 64) {                 // WxT[k][j] = Wx[j][k]
        int dd = idx >> 6, j = idx & 63;
        WxT[idx] = Wx[j * DM + dd];
    }
    if (idx < DR * DM) {                 // WdtT[r][d] = Wdt[d][r]
        int r = idx >> 9, dd = idx & 511;
        WdtT[idx] = Wdt[dd * DR + r];
    }
    if (idx < DM * DS)
        A2[idx] = -__expf(A_log[idx]) * LOG2E;
}

// ---------------- front: conv + proj1 (j2/ks8) + proj2 + bf16 pack ----------------
// 1024 blocks x 256 threads; block = 8 consecutive rows.
__global__ void __launch_bounds__(256) k_front(
        const float* __restrict__ x, const float* __restrict__ convw,
        const float* __restrict__ convb, const float* __restrict__ WxT,
        const float* __restrict__ WdtT, const float* __restrict__ dtb,
        uint32_t* __restrict__ dx, float* __restrict__ xdbl) {
    __shared__ float xcs[8][512];     // conv output tile (f32)
    __shared__ float pt[8][8][64];    // [ks][row][j] K-split partials
    __shared__ float xds[8][64];      // reduced x_dbl rows
    int t  = threadIdx.x;
    int r0 = blockIdx.x * 8;
    int b  = r0 >> 11, l0 = r0 & (L_SEQ - 1);
    int dq = t & 127, half = t >> 7;

    // ---- phase A: depthwise causal conv (K=4), float4 over d ----
    {
        const float4* wp = (const float4*)convw;
        float4 w0 = wp[dq * 4 + 0], w1 = wp[dq * 4 + 1];
        float4 w2 = wp[dq * 4 + 2], w3 = wp[dq * 4 + 3];
        float4 bias = ((const float4*)convb)[dq];
        #pragma unroll
        for (int i = 0; i < 4; ++i) {
            int row = half * 4 + i;
            int l   = l0 + row;
            const float* xr = x + ((size_t)(b * L_SEQ + l)) * DM + dq * 4;
            float4 acc = bias;
            float4 xv = *(const float4*)xr;
            acc.x = fmaf(xv.x, w0.w, acc.x); acc.y = fmaf(xv.y, w1.w, acc.y);
            acc.z = fmaf(xv.z, w2.w, acc.z); acc.w = fmaf(xv.w, w3.w, acc.w);
            if (l >= 1) {
                xv = *(const float4*)(xr - DM);
                acc.x = fmaf(xv.x, w0.z, acc.x); acc.y = fmaf(xv.y, w1.z, acc.y);
                acc.z = fmaf(xv.z, w2.z, acc.z); acc.w = fmaf(xv.w, w3.z, acc.w);
            }
            if (l >= 2) {
                xv = *(const float4*)(xr - 2 * DM);
                acc.x = fmaf(xv.x, w0.y, acc.x); acc.y = fmaf(xv.y, w1.y, acc.y);
                acc.z = fmaf(xv.z, w2.y, acc.z); acc.w = fmaf(xv.w, w3.y, acc.w);
            }
            if (l >= 3) {
                xv = *(const float4*)(xr - 3 * DM);
                acc.x = fmaf(xv.x, w0.x, acc.x); acc.y = fmaf(xv.y, w1.x, acc.y);
                acc.z = fmaf(xv.z, w2.x, acc.z); acc.w = fmaf(xv.w, w3.x, acc.w);
            }
            *(float4*)(&xcs[row][dq * 4]) = acc;
        }
    }
    __syncthreads();

    // ---- phase B: proj1 — thread owns 2 j-cols x 8 rows; 8 K-slices of 64 ----
    {
        int ks = t >> 5;                   // 0..7
        int jp = t & 31;                   // j-pair: j = 2*jp, 2*jp+1
        int k0 = ks * 64;
        float accA[8], accB[8];
        #pragma unroll
        for (int ri = 0; ri < 8; ++ri) { accA[ri] = 0.f; accB[ri] = 0.f; }
        const float2* wp2 = (const float2*)WxT;    // [k][32 pairs]
        for (int k4 = 0; k4 < 16; ++k4) {
            float4 xr[8];
            #pragma unroll
            for (int ri = 0; ri < 8; ++ri)
                xr[ri] = *(const float4*)(&xcs[ri][k0 + k4 * 4]);  // 2-addr wave broadcast
            #pragma unroll
            for (int kk = 0; kk < 4; ++kk) {
                float2 w2 = wp2[(size_t)(k0 + k4 * 4 + kk) * 32 + jp];
                #pragma unroll
                for (int ri = 0; ri < 8; ++ri) {
                    float xv = ((const float*)&xr[ri])[kk];
                    accA[ri] = fmaf(xv, w2.x, accA[ri]);
                    accB[ri] = fmaf(xv, w2.y, accB[ri]);
                }
            }
        }
        #pragma unroll
        for (int ri = 0; ri < 8; ++ri)
            *(float2*)(&pt[ks][ri][jp * 2]) = make_float2(accA[ri], accB[ri]);
    }
    __syncthreads();

    // ---- reduce the 8 K-slices -> xds + global xdbl ----
    #pragma unroll
    for (int o = t; o < 512; o += 256) {
        int row = o >> 6, j2 = o & 63;
        float s = ((pt[0][row][j2] + pt[1][row][j2]) + (pt[2][row][j2] + pt[3][row][j2]))
                + ((pt[4][row][j2] + pt[5][row][j2]) + (pt[6][row][j2] + pt[7][row][j2]));
        xds[row][j2] = s;
        xdbl[(size_t)(r0 + row) * 64 + j2] = s;
    }
    __syncthreads();

    // ---- phase C: proj2 + softplus + pack (dt|xc) bf16 ----
    {
        float4 bias = ((const float4*)dtb)[dq];
        float4 z0 = bias, z1 = bias, z2 = bias, z3 = bias;
        for (int r = 0; r < DR; ++r) {
            float4 w4 = *(const float4*)(WdtT + r * DM + dq * 4);
            float x0 = xds[half * 4 + 0][r];
            float x1 = xds[half * 4 + 1][r];
            float x2 = xds[half * 4 + 2][r];
            float x3 = xds[half * 4 + 3][r];
            z0.x = fmaf(x0, w4.x, z0.x); z0.y = fmaf(x0, w4.y, z0.y);
            z0.z = fmaf(x0, w4.z, z0.z); z0.w = fmaf(x0, w4.w, z0.w);
            z1.x = fmaf(x1, w4.x, z1.x); z1.y = fmaf(x1, w4.y, z1.y);
            z1.z = fmaf(x1, w4.z, z1.z); z1.w = fmaf(x1, w4.w, z1.w);
            z2.x = fmaf(x2, w4.x, z2.x); z2.y = fmaf(x2, w4.y, z2.y);
            z2.z = fmaf(x2, w4.z, z2.z); z2.w = fmaf(x2, w4.w, z2.w);
            z3.x = fmaf(x3, w4.x, z3.x); z3.y = fmaf(x3, w4.y, z3.y);
            z3.z = fmaf(x3, w4.z, z3.z); z3.w = fmaf(x3, w4.w, z3.w);
        }
        float4 zz[4] = {z0, z1, z2, z3};
        #pragma unroll
        for (int i = 0; i < 4; ++i) {
            int row = half * 4 + i;
            float4 zi = zz[i];
            float4 sp;
            sp.x = fmaxf(zi.x, 0.f) + log1pf(__expf(-fabsf(zi.x)));
            sp.y = fmaxf(zi.y, 0.f) + log1pf(__expf(-fabsf(zi.y)));
            sp.z = fmaxf(zi.z, 0.f) + log1pf(__expf(-fabsf(zi.z)));
            sp.w = fmaxf(zi.w, 0.f) + log1pf(__expf(-fabsf(zi.w)));
            uint4 pk;
            pk.x = bf16_rne_hi(sp.x) | (bf16_rne_hi(xcs[row][dq * 4 + 0]) >> 16);
            pk.y = bf16_rne_hi(sp.y) | (bf16_rne_hi(xcs[row][dq * 4 + 1]) >> 16);
            pk.z = bf16_rne_hi(sp.z) | (bf16_rne_hi(xcs[row][dq * 4 + 2]) >> 16);
            pk.w = bf16_rne_hi(sp.w) | (bf16_rne_hi(xcs[row][dq * 4 + 3]) >> 16);
            *(uint4*)(dx + ((size_t)(b * L_SEQ + l0 + row)) * DM + dq * 4) = pk;
        }
    }
}

// ---------------- scan1: per-chunk local scan -> S, dtsum ----------------
// grid dim3(512, 4): x = db8(3) | c(6); y = b.  2048 blocks -> 8 waves/SIMD.
__global__ void __launch_bounds__(256) k_scan1(
        const uint32_t* __restrict__ dx, const float* __restrict__ xdbl,
        const float* __restrict__ A2, float* __restrict__ S,
        float* __restrict__ dtsum) {
    int t      = threadIdx.x;
    int lane   = t & 63;
    int wv     = t >> 6;
    int dlocal = lane & 15;
    int nq     = lane >> 4;
    int db8    = blockIdx.x & 7;
    int c      = blockIdx.x >> 3;
    int b      = blockIdx.y;
    int d      = (db8 * 4 + wv) * 16 + dlocal;
    int l0     = c * CL;

    float4 a2 = *(const float4*)(A2 + (size_t)d * DS + nq * 4);
    float h0 = 0.f, h1 = 0.f, h2 = 0.f, h3 = 0.f;
    float dsum = 0.f;
    const uint32_t* dxp = dx + ((size_t)(b * L_SEQ + l0)) * DM + d;
    const float*    bp  = xdbl + ((size_t)(b * L_SEQ + l0)) * 64 + DR + nq * 4;

    #pragma unroll 8
    for (int i = 0; i < CL; ++i) {
        uint32_t v = dxp[(size_t)i * DM];
        float dt = bf_hi(v);
        float xv = bf_lo(v);
        float4 B4 = *(const float4*)(bp + (size_t)i * 64);
        float uu = dt * xv;
        dsum += dt;
        float dA;
        dA = exp2f(dt * a2.x); h0 = fmaf(dA, h0, uu * B4.x);
        dA = exp2f(dt * a2.y); h1 = fmaf(dA, h1, uu * B4.y);
        dA = exp2f(dt * a2.z); h2 = fmaf(dA, h2, uu * B4.z);
        dA = exp2f(dt * a2.w); h3 = fmaf(dA, h3, uu * B4.w);
    }
    float4 sv; sv.x = h0; sv.y = h1; sv.z = h2; sv.w = h3;
    *(float4*)(S + (size_t)c * NBDN + ((size_t)(b * DM + d)) * DS + nq * 4) = sv;
    if (nq == 0)
        dtsum[c * (NBATCH * DM) + b * DM + d] = dsum;
}

// ---------------- scan2: cross-chunk prefix; P from dtsum telescope; in-place Hin ----------------
__global__ void __launch_bounds__(256) k_scan2(
        const float* __restrict__ dtsum, const float* __restrict__ A2,
        float* __restrict__ S) {
    int t  = blockIdx.x * 256 + threadIdx.x;       // 0..32767
    float a2 = A2[t & (DM * DS - 1)];
    int bd = t >> 4;                               // b*DM+d
    float H = 0.f;
    #pragma unroll 8
    for (int cc = 0; cc < NCH; ++cc) {
        float p = exp2f(a2 * dtsum[cc * (NBATCH * DM) + bd]);
        float s = S[(size_t)cc * NBDN + t];
        S[(size_t)cc * NBDN + t] = H;              // Hin for chunk cc
        H = fmaf(p, H, s);
    }
}

// ---------------- scan3: replay chunk from Hin, emit y ----------------
__global__ void __launch_bounds__(256) k_scan3(
        const uint32_t* __restrict__ dx, const float* __restrict__ xdbl,
        const float* __restrict__ A2, const float* __restrict__ Dvec,
        const float* __restrict__ Hin, float* __restrict__ out) {
    int t      = threadIdx.x;
    int lane   = t & 63;
    int wv     = t >> 6;
    int dlocal = lane & 15;
    int nq     = lane >> 4;
    int db8    = blockIdx.x & 7;
    int c      = blockIdx.x >> 3;
    int b      = blockIdx.y;
    int d      = (db8 * 4 + wv) * 16 + dlocal;
    int l0     = c * CL;

    float4 a2 = *(const float4*)(A2 + (size_t)d * DS + nq * 4);
    float Dv = Dvec[d];
    float4 hv = *(const float4*)(Hin + (size_t)c * NBDN + ((size_t)(b * DM + d)) * DS + nq * 4);
    float h0 = hv.x, h1 = hv.y, h2 = hv.z, h3 = hv.w;

    const uint32_t* dxp = dx + ((size_t)(b * L_SEQ + l0)) * DM + d;
    const float*    bp  = xdbl + ((size_t)(b * L_SEQ + l0)) * 64 + DR + nq * 4;
    float* op = out + ((size_t)(b * L_SEQ + l0)) * DM + d;

    #pragma unroll 8
    for (int i = 0; i < CL; ++i) {
        uint32_t v = dxp[(size_t)i * DM];
        float dt = bf_hi(v);
        float xv = bf_lo(v);
        float4 B4 = *(const float4*)(bp + (size_t)i * 64);
        float4 C4 = *(const float4*)(bp + (size_t)i * 64 + DS);
        float uu = dt * xv;
        float dA;
        dA = exp2f(dt * a2.x); h0 = fmaf(dA, h0, uu * B4.x);
        dA = exp2f(dt * a2.y); h1 = fmaf(dA, h1, uu * B4.y);
        dA = exp2f(dt * a2.z); h2 = fmaf(dA, h2, uu * B4.z);
        dA = exp2f(dt * a2.w); h3 = fmaf(dA, h3, uu * B4.w);
        float p = fmaf(h3, C4.w, fmaf(h2, C4.z, fmaf(h1, C4.y, h0 * C4.x)));
        p += __shfl_xor(p, 16);
        p += __shfl_xor(p, 32);
        if (nq == 0) op[(size_t)i * DM] = fmaf(xv, Dv, p);
    }
}

extern "C" void kernel_launch(void* const* d_in, const int* in_sizes, int n_in,
                              void* d_out, int out_size, void* d_ws, size_t ws_size,
                              hipStream_t stream) {
    const float* x      = (const float*)d_in[0];
    const float* A_log  = (const float*)d_in[1];
    const float* Dvec   = (const float*)d_in[2];
    const float* Wx     = (const float*)d_in[3];
    const float* Wdt    = (const float*)d_in[4];
    const float* dtb    = (const float*)d_in[5];
    const float* convw  = (const float*)d_in[6];
    const float* convb  = (const float*)d_in[7];
    float* out = (float*)d_out;
    float* wsf = (float*)d_ws;

    uint32_t* dx    = (uint32_t*)(wsf + WS_DX);
    float*    xdbl  = wsf + WS_XDBL;
    float*    WxT   = wsf + WS_WXT;
    float*    WdtT  = wsf + WS_WDTT;
    float*    A2    = wsf + WS_A2;
    float*    dtsum = wsf + WS_DTSUM;
    float*    S     = wsf + WS_S;

    k_prep<<<128, 256, 0, stream>>>(Wx, Wdt, A_log, WxT, WdtT, A2);
    k_front<<<1024, 256, 0, stream>>>(x, convw, convb, WxT, WdtT, dtb, dx, xdbl);
    k_scan1<<<dim3(512, 4), 256, 0, stream>>>(dx, xdbl, A2, S, dtsum);
    k_scan2<<<128, 256, 0, stream>>>(dtsum, A2, S);
    k_scan3<<<dim3(512, 4), 256, 0, stream>>>(dx, xdbl, A2, Dvec, S, out);
}